// Round 1
// baseline (3783.538 us; speedup 1.0000x reference)
//
#include <hip/hip_runtime.h>

#define NF1 10
#define NCPF1 3
#define G1 145
#define NF2 6
#define NCPF2 100
#define G2 1506

// Build perm-group index tables: group g = y[piv[g]] + S[kk[g]] - y[kj[g]]
__global__ void build_tables(int* __restrict__ piv1, int* __restrict__ kk1, int* __restrict__ kj1,
                             int* __restrict__ piv2, int* __restrict__ kk2, int* __restrict__ kj2) {
  int t = threadIdx.x;
  if (t < NF1) {
    int i = t;
    int base = 0;
    for (int ii = 0; ii < i; ++ii) base += (NF1 - ii) + (NCPF1 - 1) * (NF1 - 1 - ii);
    int count = base;
    for (int j = 0; j < NCPF1; ++j) {
      int k0 = (j == 0) ? i : (i + 1);
      for (int k = k0; k < NF1; ++k) {
        piv1[count] = i * NCPF1 + j;
        kk1[count] = k;
        kj1[count] = k * NCPF1 + j;
        ++count;
      }
    }
  }
  if (t >= 32 && t < 32 + NF2) {
    int i = t - 32;
    int base = 0;
    for (int ii = 0; ii < i; ++ii) base += (NF2 - ii) + (NCPF2 - 1) * (NF2 - 1 - ii);
    int count = base;
    for (int j = 0; j < NCPF2; ++j) {
      int k0 = (j == 0) ? i : (i + 1);
      for (int k = k0; k < NF2; ++k) {
        piv2[count] = i * NCPF2 + j;
        kk2[count] = k;
        kj2[count] = k * NCPF2 + j;
        ++count;
      }
    }
  }
}

// Depthwise-ish conv stage 1: x[b,3,32,32] -> y[b,30,32,32], oc -> ic = oc/10
__global__ __launch_bounds__(256) void dwconv1(const float* __restrict__ x, const float* __restrict__ w,
                                               const float* __restrict__ bias, float* __restrict__ y, int nimg) {
  int idx = blockIdx.x * 256 + threadIdx.x;
  int total = nimg * 30 * 1024;
  if (idx >= total) return;
  int wc = idx & 31;
  int h = (idx >> 5) & 31;
  int c = (idx >> 10) % 30;
  int b = idx / (30 * 1024);
  int ic = c / 10;
  const float* xp = x + ((size_t)b * 3 + ic) * 1024;
  const float* wp = w + c * 9;
  float acc = bias[c];
#pragma unroll
  for (int kh = 0; kh < 3; ++kh) {
    int hh = h + kh - 1;
    if (hh < 0 || hh > 31) continue;
#pragma unroll
    for (int kw = 0; kw < 3; ++kw) {
      int ww = wc + kw - 1;
      if (ww < 0 || ww > 31) continue;
      acc += xp[hh * 32 + ww] * wp[kh * 3 + kw];
    }
  }
  y[idx] = acc;
}

// Stage 1 fused: perm-sum -> relu -> pw1 -> +bias -> relu -> 2x2 maxpool
// block = (b, oh); handles input rows 2*oh, 2*oh+1 (64 pixels), outputs h1[b,100,oh,0..15]
__global__ __launch_bounds__(256) void stage1(const float* __restrict__ y1, const float* __restrict__ pw_w,
                                              const float* __restrict__ pw_b, const int* __restrict__ piv,
                                              const int* __restrict__ kk, const int* __restrict__ kj,
                                              float* __restrict__ h1) {
  __shared__ float ys[30][64];
  __shared__ float Ss[NF1][64];
  __shared__ float gs[G1][64];
  int b = blockIdx.x >> 4;
  int oh = blockIdx.x & 15;
  int t = threadIdx.x;
  const float* yb = y1 + (size_t)b * 30 * 1024 + oh * 64;  // rows 2oh,2oh+1 contiguous
  for (int idx = t; idx < 30 * 64; idx += 256) {
    int c = idx >> 6, p = idx & 63;
    ys[c][p] = yb[c * 1024 + p];
  }
  __syncthreads();
  for (int idx = t; idx < NF1 * 64; idx += 256) {
    int f = idx >> 6, p = idx & 63;
    Ss[f][p] = ys[3 * f][p] + ys[3 * f + 1][p] + ys[3 * f + 2][p];
  }
  __syncthreads();
  for (int idx = t; idx < G1 * 64; idx += 256) {
    int gr = idx >> 6, p = idx & 63;
    float v = ys[piv[gr]][p] + Ss[kk[gr]][p] - ys[kj[gr]][p];
    gs[gr][p] = fmaxf(v, 0.0f);
  }
  __syncthreads();
  for (int item = t; item < 100 * 16; item += 256) {
    int oc = item >> 4, ow = item & 15;
    const float* wr = pw_w + oc * G1;
    float a0 = 0.f, a1 = 0.f, a2 = 0.f, a3 = 0.f;
    for (int gr = 0; gr < G1; ++gr) {
      float wv = wr[gr];
      float2 ga = *(const float2*)&gs[gr][2 * ow];
      float2 gb = *(const float2*)&gs[gr][32 + 2 * ow];
      a0 += wv * ga.x;
      a1 += wv * ga.y;
      a2 += wv * gb.x;
      a3 += wv * gb.y;
    }
    float m = fmaxf(fmaxf(a0, a1), fmaxf(a2, a3)) + pw_b[oc];
    h1[(((size_t)b * 100 + oc) * 16 + oh) * 16 + ow] = fmaxf(m, 0.0f);
  }
}

// Depthwise-ish conv stage 2: h1[b,100,16,16] -> y2[b,600,16,16], oc -> ic = oc/6
__global__ __launch_bounds__(256) void dwconv2(const float* __restrict__ h1, const float* __restrict__ w,
                                               const float* __restrict__ bias, float* __restrict__ y2, int nimg) {
  int idx = blockIdx.x * 256 + threadIdx.x;
  int total = nimg * 600 * 256;
  if (idx >= total) return;
  int wc = idx & 15;
  int h = (idx >> 4) & 15;
  int c = (idx >> 8) % 600;
  int b = idx / (600 * 256);
  int ic = c / 6;
  const float* xp = h1 + ((size_t)b * 100 + ic) * 256;
  const float* wp = w + c * 9;
  float acc = bias[c];
#pragma unroll
  for (int kh = 0; kh < 3; ++kh) {
    int hh = h + kh - 1;
    if (hh < 0 || hh > 15) continue;
#pragma unroll
    for (int kw = 0; kw < 3; ++kw) {
      int ww = wc + kw - 1;
      if (ww < 0 || ww > 15) continue;
      acc += xp[hh * 16 + ww] * wp[kh * 3 + kw];
    }
  }
  y2[idx] = acc;
}

// transpose pw2_w [300][1506] -> wT [1506][300] for coalesced weight reads
__global__ __launch_bounds__(256) void transpose_w(const float* __restrict__ pw2w, float* __restrict__ wT) {
  int idx = blockIdx.x * 256 + threadIdx.x;
  if (idx >= 300 * G2) return;
  int gr = idx / 300, oc = idx % 300;
  wT[idx] = pw2w[oc * G2 + gr];
}

// Stage 2 fused: perm-sum -> relu -> pw2 -> +bias -> relu -> 2x2 maxpool
// block = (b, oh); input rows 2oh,2oh+1 (32 pixels), outputs h2[b,300,oh,0..7]
__global__ __launch_bounds__(256) void stage2(const float* __restrict__ y2, const float* __restrict__ wT,
                                              const float* __restrict__ pw_b, const int* __restrict__ piv,
                                              const int* __restrict__ kk, const int* __restrict__ kj,
                                              float* __restrict__ h2) {
  __shared__ float Ss[NF2][32];
  __shared__ float gs[32][34];
  int b = blockIdx.x >> 3;
  int oh = blockIdx.x & 7;
  int t = threadIdx.x;
  const float* yb = y2 + (size_t)b * 600 * 256 + oh * 32;  // channel c: yb[c*256 + p], p in [0,32)
  // per-filter channel sums (6 filters x 100 channels)
  for (int idx = t; idx < NF2 * 32; idx += 256) {
    int k = idx >> 5, p = idx & 31;
    const float* cp = yb + k * 100 * 256 + p;
    float s = 0.f;
    for (int m = 0; m < 100; ++m) s += cp[m * 256];
    Ss[k][p] = s;
  }
  int to = t >> 3;  // 0..31 -> oc = to + 32u
  int ow = t & 7;   // output col; input cols 2ow,2ow+1
  float acc[10][4];
#pragma unroll
  for (int u = 0; u < 10; ++u)
#pragma unroll
    for (int q = 0; q < 4; ++q) acc[u][q] = 0.f;
  for (int tile = 0; tile < (G2 + 31) / 32; ++tile) {
    int gbase = tile * 32;
    __syncthreads();  // Ss ready (first iter) / previous gs reads done
    for (int idx = t; idx < 32 * 32; idx += 256) {
      int gl = idx >> 5, p = idx & 31;
      int gr = gbase + gl;
      float v = 0.f;
      if (gr < G2) {
        v = yb[piv[gr] * 256 + p] + Ss[kk[gr]][p] - yb[kj[gr] * 256 + p];
        v = fmaxf(v, 0.f);
      }
      gs[gl][p] = v;
    }
    __syncthreads();
    int gcnt = G2 - gbase;
    if (gcnt > 32) gcnt = 32;
    for (int gl = 0; gl < gcnt; ++gl) {
      int gr = gbase + gl;
      float2 ga = *(const float2*)&gs[gl][2 * ow];
      float2 gb = *(const float2*)&gs[gl][16 + 2 * ow];
      const float* wrow = wT + (size_t)gr * 300;
#pragma unroll
      for (int u = 0; u < 9; ++u) {
        float wv = wrow[to + 32 * u];
        acc[u][0] += wv * ga.x;
        acc[u][1] += wv * ga.y;
        acc[u][2] += wv * gb.x;
        acc[u][3] += wv * gb.y;
      }
      if (to < 12) {
        float wv = wrow[288 + to];
        acc[9][0] += wv * ga.x;
        acc[9][1] += wv * ga.y;
        acc[9][2] += wv * gb.x;
        acc[9][3] += wv * gb.y;
      }
    }
  }
#pragma unroll
  for (int u = 0; u < 10; ++u) {
    int oc = to + 32 * u;
    if (oc < 300) {
      float m = fmaxf(fmaxf(acc[u][0], acc[u][1]), fmaxf(acc[u][2], acc[u][3])) + pw_b[oc];
      h2[(((size_t)b * 300 + oc) * 8 + oh) * 8 + ow] = fmaxf(m, 0.f);
    }
  }
}

// Fold fc2 @ fc1 -> combW [10,19200], combB [10]
__global__ __launch_bounds__(256) void fold_fc(const float* __restrict__ fc1w, const float* __restrict__ fc2w,
                                               float* __restrict__ combW) {
  int idx = blockIdx.x * 256 + threadIdx.x;
  if (idx >= 10 * 19200) return;
  int o = idx / 19200, c = idx % 19200;
  float s = 0.f;
  for (int m = 0; m < 120; ++m) s += fc2w[o * 120 + m] * fc1w[m * 19200 + c];
  combW[idx] = s;
}

__global__ void fold_b(const float* __restrict__ fc1b, const float* __restrict__ fc2w,
                       const float* __restrict__ fc2b, float* __restrict__ combB) {
  int o = threadIdx.x;
  if (o < 10) {
    float s = fc2b[o];
    for (int m = 0; m < 120; ++m) s += fc2w[o * 120 + m] * fc1b[m];
    combB[o] = s;
  }
}

// out[b,o] = combB[o] + dot(h2flat[b], combW[o])
__global__ __launch_bounds__(256) void fc_out(const float* __restrict__ h2, const float* __restrict__ combW,
                                              const float* __restrict__ combB, float* __restrict__ out, int b0) {
  int b = blockIdx.x / 10, o = blockIdx.x % 10;
  const float* hp = h2 + (size_t)b * 19200;
  const float* wp = combW + (size_t)o * 19200;
  float s = 0.f;
  for (int i = threadIdx.x; i < 19200; i += 256) s += hp[i] * wp[i];
  __shared__ float red[256];
  red[threadIdx.x] = s;
  __syncthreads();
  for (int stride = 128; stride > 0; stride >>= 1) {
    if (threadIdx.x < stride) red[threadIdx.x] += red[threadIdx.x + stride];
    __syncthreads();
  }
  if (threadIdx.x == 0) out[(size_t)(b0 + b) * 10 + o] = red[0] + combB[o];
}

extern "C" void kernel_launch(void* const* d_in, const int* in_sizes, int n_in,
                              void* d_out, int out_size, void* d_ws, size_t ws_size,
                              hipStream_t stream) {
  const float* x = (const float*)d_in[0];
  const float* dw1w = (const float*)d_in[1];
  const float* dw1b = (const float*)d_in[2];
  const float* pw1w = (const float*)d_in[3];
  const float* pw1b = (const float*)d_in[4];
  const float* dw2w = (const float*)d_in[5];
  const float* dw2b = (const float*)d_in[6];
  const float* pw2w = (const float*)d_in[7];
  const float* pw2b = (const float*)d_in[8];
  const float* fc1w = (const float*)d_in[9];
  const float* fc1b = (const float*)d_in[10];
  const float* fc2w = (const float*)d_in[11];
  const float* fc2b = (const float*)d_in[12];
  float* out = (float*)d_out;

  char* ws = (char*)d_ws;
  size_t off = 0;
  auto alloc = [&](size_t bytes) -> void* {
    off = (off + 255) & ~(size_t)255;
    void* p = ws + off;
    off += bytes;
    return p;
  };
  int* piv1 = (int*)alloc(G1 * 4);
  int* kk1 = (int*)alloc(G1 * 4);
  int* kj1 = (int*)alloc(G1 * 4);
  int* piv2 = (int*)alloc(G2 * 4);
  int* kk2 = (int*)alloc(G2 * 4);
  int* kj2 = (int*)alloc(G2 * 4);
  float* combW = (float*)alloc((size_t)10 * 19200 * 4);
  float* combB = (float*)alloc(16 * 4);
  float* wT = (float*)alloc((size_t)G2 * 300 * 4);
  size_t static_end = (off + 255) & ~(size_t)255;

  // per-image floats: y1 30*1024, h1 100*256, y2 600*256, h2 300*64
  size_t per_img = (size_t)(30 * 1024 + 100 * 256 + 600 * 256 + 300 * 64) * 4;
  long long avail = (long long)ws_size - (long long)static_end - 8192;
  int CB = 1;
  if (avail > 0) {
    long long c = avail / (long long)(per_img + 1024);
    if (c > 500) c = 500;
    if (c < 1) c = 1;
    CB = (int)c;
  }
  float* y1 = (float*)alloc((size_t)CB * 30 * 1024 * 4);
  float* h1 = (float*)alloc((size_t)CB * 100 * 256 * 4);
  float* y2b = (float*)alloc((size_t)CB * 600 * 256 * 4);
  float* h2 = (float*)alloc((size_t)CB * 300 * 64 * 4);

  build_tables<<<1, 64, 0, stream>>>(piv1, kk1, kj1, piv2, kk2, kj2);
  fold_fc<<<(10 * 19200 + 255) / 256, 256, 0, stream>>>(fc1w, fc2w, combW);
  fold_b<<<1, 64, 0, stream>>>(fc1b, fc2w, fc2b, combB);
  transpose_w<<<(300 * G2 + 255) / 256, 256, 0, stream>>>(pw2w, wT);

  for (int b0 = 0; b0 < 500; b0 += CB) {
    int nb = 500 - b0 < CB ? 500 - b0 : CB;
    dwconv1<<<(nb * 30 * 1024 + 255) / 256, 256, 0, stream>>>(x + (size_t)b0 * 3 * 1024, dw1w, dw1b, y1, nb);
    stage1<<<nb * 16, 256, 0, stream>>>(y1, pw1w, pw1b, piv1, kk1, kj1, h1);
    dwconv2<<<nb * 600, 256, 0, stream>>>(h1, dw2w, dw2b, y2b, nb);
    stage2<<<nb * 8, 256, 0, stream>>>(y2b, wT, pw2b, piv2, kk2, kj2, h2);
    fc_out<<<nb * 10, 256, 0, stream>>>(h2, combW, combB, out, b0);
  }
}

// Round 2
// 2768.041 us; speedup vs baseline: 1.3669x; 1.3669x over previous
//
#include <hip/hip_runtime.h>

#define NF1 10
#define NCPF1 3
#define G1 145
#define NF2 6
#define NCPF2 100
#define G2 1506
#define KTOT 1536
#define NKT 24
#define SLP 264

typedef __attribute__((ext_vector_type(8))) short bf16x8;
typedef __attribute__((ext_vector_type(4))) float f32x4;

__device__ __forceinline__ void bsplit(float v, ushort& h, ushort& l) {
  union { float f; uint u; } a; a.f = v;
  uint hu = (a.u + 0x7fffu + ((a.u >> 16) & 1u)) >> 16;  // RNE to bf16
  union { uint u; float f; } hf; hf.u = hu << 16;
  h = (ushort)hu;
  float r = v - hf.f;
  union { float f; uint u; } b2; b2.f = r;
  uint lu = (b2.u + 0x7fffu + ((b2.u >> 16) & 1u)) >> 16;
  l = (ushort)lu;
}

// n (MFMA column 0..255) -> pixel index in 16x16 image. Quad-grouped so the
// 2x2 pool partners share a lane across the 4 nt-tiles.
__device__ __forceinline__ int pixmap(int n) {
  int quad = ((n >> 6) << 4) | (n & 15);
  int nt = (n >> 4) & 3;
  int h = ((quad >> 3) << 1) | (nt >> 1);
  int w = ((quad & 7) << 1) | (nt & 1);
  return h * 16 + w;
}

// Build perm-group index tables: group g = y[piv[g]] + S[kk[g]] - y[kj[g]]
__global__ void build_tables(int* __restrict__ piv1, int* __restrict__ kk1, int* __restrict__ kj1,
                             int* __restrict__ piv2, int* __restrict__ kk2, int* __restrict__ kj2) {
  int t = threadIdx.x;
  if (t < NF1) {
    int i = t;
    int base = 0;
    for (int ii = 0; ii < i; ++ii) base += (NF1 - ii) + (NCPF1 - 1) * (NF1 - 1 - ii);
    int count = base;
    for (int j = 0; j < NCPF1; ++j) {
      int k0 = (j == 0) ? i : (i + 1);
      for (int k = k0; k < NF1; ++k) {
        piv1[count] = i * NCPF1 + j;
        kk1[count] = k;
        kj1[count] = k * NCPF1 + j;
        ++count;
      }
    }
  }
  if (t >= 32 && t < 32 + NF2) {
    int i = t - 32;
    int base = 0;
    for (int ii = 0; ii < i; ++ii) base += (NF2 - ii) + (NCPF2 - 1) * (NF2 - 1 - ii);
    int count = base;
    for (int j = 0; j < NCPF2; ++j) {
      int k0 = (j == 0) ? i : (i + 1);
      for (int k = k0; k < NF2; ++k) {
        piv2[count] = i * NCPF2 + j;
        kk2[count] = k;
        kj2[count] = k * NCPF2 + j;
        ++count;
      }
    }
  }
}

__global__ __launch_bounds__(256) void dwconv1(const float* __restrict__ x, const float* __restrict__ w,
                                               const float* __restrict__ bias, float* __restrict__ y, int nimg) {
  int idx = blockIdx.x * 256 + threadIdx.x;
  int total = nimg * 30 * 1024;
  if (idx >= total) return;
  int wc = idx & 31;
  int h = (idx >> 5) & 31;
  int c = (idx >> 10) % 30;
  int b = idx / (30 * 1024);
  int ic = c / 10;
  const float* xp = x + ((size_t)b * 3 + ic) * 1024;
  const float* wp = w + c * 9;
  float acc = bias[c];
#pragma unroll
  for (int kh = 0; kh < 3; ++kh) {
    int hh = h + kh - 1;
    if (hh < 0 || hh > 31) continue;
#pragma unroll
    for (int kw = 0; kw < 3; ++kw) {
      int ww = wc + kw - 1;
      if (ww < 0 || ww > 31) continue;
      acc += xp[hh * 32 + ww] * wp[kh * 3 + kw];
    }
  }
  y[idx] = acc;
}

__global__ __launch_bounds__(256) void stage1(const float* __restrict__ y1, const float* __restrict__ pw_w,
                                              const float* __restrict__ pw_b, const int* __restrict__ piv,
                                              const int* __restrict__ kk, const int* __restrict__ kj,
                                              float* __restrict__ h1) {
  __shared__ float ys[30][64];
  __shared__ float Ss[NF1][64];
  __shared__ float gs[G1][64];
  int b = blockIdx.x >> 4;
  int oh = blockIdx.x & 15;
  int t = threadIdx.x;
  const float* yb = y1 + (size_t)b * 30 * 1024 + oh * 64;
  for (int idx = t; idx < 30 * 64; idx += 256) {
    int c = idx >> 6, p = idx & 63;
    ys[c][p] = yb[c * 1024 + p];
  }
  __syncthreads();
  for (int idx = t; idx < NF1 * 64; idx += 256) {
    int f = idx >> 6, p = idx & 63;
    Ss[f][p] = ys[3 * f][p] + ys[3 * f + 1][p] + ys[3 * f + 2][p];
  }
  __syncthreads();
  for (int idx = t; idx < G1 * 64; idx += 256) {
    int gr = idx >> 6, p = idx & 63;
    float v = ys[piv[gr]][p] + Ss[kk[gr]][p] - ys[kj[gr]][p];
    gs[gr][p] = fmaxf(v, 0.0f);
  }
  __syncthreads();
  for (int item = t; item < 100 * 16; item += 256) {
    int oc = item >> 4, ow = item & 15;
    const float* wr = pw_w + oc * G1;
    float a0 = 0.f, a1 = 0.f, a2 = 0.f, a3 = 0.f;
    for (int gr = 0; gr < G1; ++gr) {
      float wv = wr[gr];
      float2 ga = *(const float2*)&gs[gr][2 * ow];
      float2 gb = *(const float2*)&gs[gr][32 + 2 * ow];
      a0 += wv * ga.x;
      a1 += wv * ga.y;
      a2 += wv * gb.x;
      a3 += wv * gb.y;
    }
    float m = fmaxf(fmaxf(a0, a1), fmaxf(a2, a3)) + pw_b[oc];
    h1[(((size_t)b * 100 + oc) * 16 + oh) * 16 + ow] = fmaxf(m, 0.0f);
  }
}

__global__ __launch_bounds__(256) void dwconv2(const float* __restrict__ h1, const float* __restrict__ w,
                                               const float* __restrict__ bias, float* __restrict__ y2, int nimg) {
  int idx = blockIdx.x * 256 + threadIdx.x;
  int total = nimg * 600 * 256;
  if (idx >= total) return;
  int wc = idx & 15;
  int h = (idx >> 4) & 15;
  int c = (idx >> 8) % 600;
  int b = idx / (600 * 256);
  int ic = c / 6;
  const float* xp = h1 + ((size_t)b * 100 + ic) * 256;
  const float* wp = w + c * 9;
  float acc = bias[c];
#pragma unroll
  for (int kh = 0; kh < 3; ++kh) {
    int hh = h + kh - 1;
    if (hh < 0 || hh > 15) continue;
#pragma unroll
    for (int kw = 0; kw < 3; ++kw) {
      int ww = wc + kw - 1;
      if (ww < 0 || ww > 15) continue;
      acc += xp[hh * 16 + ww] * wp[kh * 3 + kw];
    }
  }
  y2[idx] = acc;
}

// per-filter channel sums, coalesced: S2[b][f][p] = sum_{m<100} y2[b][f*100+m][p]
__global__ __launch_bounds__(256) void sfilt(const float* __restrict__ y2, float* __restrict__ S2, int nimg) {
  int idx = blockIdx.x * 256 + threadIdx.x;
  if (idx >= nimg * 6 * 256) return;
  int p = idx & 255;
  int f = (idx >> 8) % 6;
  int b = idx / (6 * 256);
  const float* cp = y2 + (size_t)b * 600 * 256 + f * 100 * 256 + p;
  float s = 0.f;
  for (int m = 0; m < 100; ++m) s += cp[m * 256];
  S2[idx] = s;
}

// split pw2 weights into bf16 hi/lo planes, padded [320][1536]
__global__ __launch_bounds__(256) void prep_w2(const float* __restrict__ pw2w, ushort* __restrict__ whi,
                                               ushort* __restrict__ wlo) {
  int idx = blockIdx.x * 256 + threadIdx.x;
  if (idx >= 320 * KTOT) return;
  int oc = idx / KTOT, k = idx % KTOT;
  float v = (oc < 300 && k < G2) ? pw2w[oc * G2 + k] : 0.f;
  ushort h, l;
  bsplit(v, h, l);
  whi[idx] = h;
  wlo[idx] = l;
}

// Stage-2 fused MFMA kernel: build G tile in LDS (bf16 hi/lo, XOR-swizzled),
// 3-term split-precision MFMA into f32, pool+bias+relu epilogue.
// grid = nimg * 2 (two 160-oc halves), block = 512 (8 waves = 2M x 4N)
__global__ __launch_bounds__(512, 1) void stage2_mfma(
    const float* __restrict__ y2, const ushort* __restrict__ whi, const ushort* __restrict__ wlo,
    const float* __restrict__ S2, const float* __restrict__ pw_b, const int* __restrict__ piv,
    const int* __restrict__ kk, const int* __restrict__ kj, float* __restrict__ h2) {
  extern __shared__ char smem[];
  ushort* ghh = (ushort*)smem;                    // 256x64 bf16 hi, swizzled  (32 KB)
  ushort* gll = (ushort*)(smem + 32768);          // lo plane                  (32 KB)
  float* Slp = (float*)(smem + 65536);            // [6][SLP] filter sums      (6.3 KB)
  int* pvT = (int*)(smem + 65536 + 6 * SLP * 4);  // 64-entry per-ktile tables
  int* kkT = pvT + 64;
  int* kjT = kkT + 64;

  int b = blockIdx.x >> 1;
  int mg = blockIdx.x & 1;
  int t = threadIdx.x;
  const float* yb = y2 + (size_t)b * 600 * 256;

  for (int i = t; i < 6 * 256; i += 512) {
    int f = i >> 8, n = i & 255;
    Slp[f * SLP + n] = S2[((size_t)b * 6 + f) * 256 + pixmap(n)];
  }
  if (t < 64) {
    int g = t;
    pvT[t] = (g < G2) ? piv[g] : 0;
    kkT[t] = (g < G2) ? kk[g] : 0;
    kjT[t] = (g < G2) ? kj[g] : 0;
  }

  int lane = t & 63, wave = t >> 6;
  int wm = wave >> 2, wn = wave & 3;
  int lrow = lane & 15, lkk = lane >> 4;
  int dk = lane >> 3, dn = lane & 7;

  f32x4 acc[5][4];
#pragma unroll
  for (int mt = 0; mt < 5; ++mt)
#pragma unroll
    for (int nt = 0; nt < 4; ++nt) acc[mt][nt] = (f32x4){0.f, 0.f, 0.f, 0.f};

  for (int kt = 0; kt < NKT; ++kt) {
    int kb = kt * 64;
    __syncthreads();  // miniT/Sl ready; previous compute's LDS reads done

    // ---- G build: thread covers 8 k (dk octet) x 4 n strips ----
    int pv8[8], kk8[8], kj8[8];
#pragma unroll
    for (int c = 0; c < 8; ++c) {
      int k = dk * 8 + c;
      pv8[c] = pvT[k];
      kk8[c] = kkT[k];
      kj8[c] = kjT[k];
    }
#pragma unroll
    for (int i = 0; i < 4; ++i) {
      int n = wave * 32 + i * 8 + dn;
      int p = pixmap(n);
      const float* ybp = yb + p;
      bf16x8 vh, vl;
#pragma unroll
      for (int c = 0; c < 8; ++c) {
        int gr = kb + dk * 8 + c;
        float v = 0.f;
        if (gr < G2) v = fmaxf(ybp[pv8[c] * 256] + Slp[kk8[c] * SLP + n] - ybp[kj8[c] * 256], 0.f);
        ushort h, l;
        bsplit(v, h, l);
        vh[c] = (short)h;
        vl[c] = (short)l;
      }
      uint off = ((uint)(n * 128 + dk * 16)) ^ ((uint)(n & 7) << 4);
      *(bf16x8*)((char*)ghh + off) = vh;
      *(bf16x8*)((char*)gll + off) = vl;
    }
    __syncthreads();

    // ---- B preload (16 frags from swizzled LDS) ----
    bf16x8 Bh[4][2], Bl[4][2];
#pragma unroll
    for (int nt = 0; nt < 4; ++nt) {
      int n = wn * 64 + nt * 16 + lrow;
#pragma unroll
      for (int ks = 0; ks < 2; ++ks) {
        uint off = ((uint)(n * 128 + (ks * 32 + lkk * 8) * 2)) ^ ((uint)(n & 7) << 4);
        Bh[nt][ks] = *(const bf16x8*)((char*)ghh + off);
        Bl[nt][ks] = *(const bf16x8*)((char*)gll + off);
      }
    }

    // prefetch next ktile's tables (ordered by next top barrier)
    if (t < 64 && kt + 1 < NKT) {
      int g = (kt + 1) * 64 + t;
      pvT[t] = (g < G2) ? piv[g] : 0;
      kkT[t] = (g < G2) ? kk[g] : 0;
      kjT[t] = (g < G2) ? kj[g] : 0;
    }

    // ---- MFMA: A frags straight from L2-resident weight planes ----
#pragma unroll
    for (int mt = 0; mt < 5; ++mt) {
      int row = mg * 160 + wm * 80 + mt * 16 + lrow;
      const ushort* wp0 = whi + (size_t)row * KTOT + kb + lkk * 8;
      const ushort* wp1 = wlo + (size_t)row * KTOT + kb + lkk * 8;
      bf16x8 Ah0 = *(const bf16x8*)wp0;
      bf16x8 Ah1 = *(const bf16x8*)(wp0 + 32);
      bf16x8 Al0 = *(const bf16x8*)wp1;
      bf16x8 Al1 = *(const bf16x8*)(wp1 + 32);
#pragma unroll
      for (int nt = 0; nt < 4; ++nt) {
        f32x4 c = acc[mt][nt];
        c = __builtin_amdgcn_mfma_f32_16x16x32_bf16(Ah0, Bh[nt][0], c, 0, 0, 0);
        c = __builtin_amdgcn_mfma_f32_16x16x32_bf16(Ah1, Bh[nt][1], c, 0, 0, 0);
        c = __builtin_amdgcn_mfma_f32_16x16x32_bf16(Al0, Bh[nt][0], c, 0, 0, 0);
        c = __builtin_amdgcn_mfma_f32_16x16x32_bf16(Al1, Bh[nt][1], c, 0, 0, 0);
        c = __builtin_amdgcn_mfma_f32_16x16x32_bf16(Ah0, Bl[nt][0], c, 0, 0, 0);
        c = __builtin_amdgcn_mfma_f32_16x16x32_bf16(Ah1, Bl[nt][1], c, 0, 0, 0);
        acc[mt][nt] = c;
      }
    }
  }

  // ---- epilogue: 2x2 pool across nt (in-lane), bias, relu, store ----
#pragma unroll
  for (int mt = 0; mt < 5; ++mt) {
#pragma unroll
    for (int r = 0; r < 4; ++r) {
      float m4 = fmaxf(fmaxf(acc[mt][0][r], acc[mt][1][r]), fmaxf(acc[mt][2][r], acc[mt][3][r]));
      int oc = mg * 160 + wm * 80 + mt * 16 + lkk * 4 + r;
      if (oc < 300) {
        int quad = wn * 16 + lrow;
        h2[((size_t)b * 300 + oc) * 64 + quad] = fmaxf(m4 + pw_b[oc], 0.f);
      }
    }
  }
}

__global__ __launch_bounds__(256) void fold_fc(const float* __restrict__ fc1w, const float* __restrict__ fc2w,
                                               float* __restrict__ combW) {
  int idx = blockIdx.x * 256 + threadIdx.x;
  if (idx >= 10 * 19200) return;
  int o = idx / 19200, c = idx % 19200;
  float s = 0.f;
  for (int m = 0; m < 120; ++m) s += fc2w[o * 120 + m] * fc1w[m * 19200 + c];
  combW[idx] = s;
}

__global__ void fold_b(const float* __restrict__ fc1b, const float* __restrict__ fc2w,
                       const float* __restrict__ fc2b, float* __restrict__ combB) {
  int o = threadIdx.x;
  if (o < 10) {
    float s = fc2b[o];
    for (int m = 0; m < 120; ++m) s += fc2w[o * 120 + m] * fc1b[m];
    combB[o] = s;
  }
}

__global__ __launch_bounds__(256) void fc_out(const float* __restrict__ h2, const float* __restrict__ combW,
                                              const float* __restrict__ combB, float* __restrict__ out, int b0) {
  int b = blockIdx.x / 10, o = blockIdx.x % 10;
  const float* hp = h2 + (size_t)b * 19200;
  const float* wp = combW + (size_t)o * 19200;
  float s = 0.f;
  for (int i = threadIdx.x; i < 19200; i += 256) s += hp[i] * wp[i];
  __shared__ float red[256];
  red[threadIdx.x] = s;
  __syncthreads();
  for (int stride = 128; stride > 0; stride >>= 1) {
    if (threadIdx.x < stride) red[threadIdx.x] += red[threadIdx.x + stride];
    __syncthreads();
  }
  if (threadIdx.x == 0) out[(size_t)(b0 + b) * 10 + o] = red[0] + combB[o];
}

extern "C" void kernel_launch(void* const* d_in, const int* in_sizes, int n_in,
                              void* d_out, int out_size, void* d_ws, size_t ws_size,
                              hipStream_t stream) {
  const float* x = (const float*)d_in[0];
  const float* dw1w = (const float*)d_in[1];
  const float* dw1b = (const float*)d_in[2];
  const float* pw1w = (const float*)d_in[3];
  const float* pw1b = (const float*)d_in[4];
  const float* dw2w = (const float*)d_in[5];
  const float* dw2b = (const float*)d_in[6];
  const float* pw2w = (const float*)d_in[7];
  const float* pw2b = (const float*)d_in[8];
  const float* fc1w = (const float*)d_in[9];
  const float* fc1b = (const float*)d_in[10];
  const float* fc2w = (const float*)d_in[11];
  const float* fc2b = (const float*)d_in[12];
  float* out = (float*)d_out;

  char* ws = (char*)d_ws;
  size_t off = 0;
  auto alloc = [&](size_t bytes) -> void* {
    off = (off + 255) & ~(size_t)255;
    void* p = ws + off;
    off += bytes;
    return p;
  };
  int* piv1 = (int*)alloc(G1 * 4);
  int* kk1 = (int*)alloc(G1 * 4);
  int* kj1 = (int*)alloc(G1 * 4);
  int* piv2 = (int*)alloc(G2 * 4);
  int* kk2 = (int*)alloc(G2 * 4);
  int* kj2 = (int*)alloc(G2 * 4);
  float* combW = (float*)alloc((size_t)10 * 19200 * 4);
  float* combB = (float*)alloc(16 * 4);
  ushort* whi = (ushort*)alloc((size_t)320 * KTOT * 2);
  ushort* wlo = (ushort*)alloc((size_t)320 * KTOT * 2);
  size_t static_end = (off + 255) & ~(size_t)255;

  // per-image floats: y1 30*1024, h1 100*256, y2 600*256, h2 300*64, S2 6*256
  size_t per_img = (size_t)(30 * 1024 + 100 * 256 + 600 * 256 + 300 * 64 + 6 * 256) * 4;
  long long avail = (long long)ws_size - (long long)static_end - 8192;
  int CB = 1;
  if (avail > 0) {
    long long c = avail / (long long)(per_img + 1024);
    if (c > 500) c = 500;
    if (c < 1) c = 1;
    CB = (int)c;
  }
  float* y1 = (float*)alloc((size_t)CB * 30 * 1024 * 4);
  float* h1 = (float*)alloc((size_t)CB * 100 * 256 * 4);
  float* y2b = (float*)alloc((size_t)CB * 600 * 256 * 4);
  float* h2 = (float*)alloc((size_t)CB * 300 * 64 * 4);
  float* S2 = (float*)alloc((size_t)CB * 6 * 256 * 4);

  build_tables<<<1, 64, 0, stream>>>(piv1, kk1, kj1, piv2, kk2, kj2);
  fold_fc<<<(10 * 19200 + 255) / 256, 256, 0, stream>>>(fc1w, fc2w, combW);
  fold_b<<<1, 64, 0, stream>>>(fc1b, fc2w, fc2b, combB);
  prep_w2<<<(320 * KTOT + 255) / 256, 256, 0, stream>>>(pw2w, whi, wlo);

  const uint smem2 = 65536 + 6 * SLP * 4 + 3 * 64 * 4;

  for (int b0 = 0; b0 < 500; b0 += CB) {
    int nb = 500 - b0 < CB ? 500 - b0 : CB;
    dwconv1<<<(nb * 30 * 1024 + 255) / 256, 256, 0, stream>>>(x + (size_t)b0 * 3 * 1024, dw1w, dw1b, y1, nb);
    stage1<<<nb * 16, 256, 0, stream>>>(y1, pw1w, pw1b, piv1, kk1, kj1, h1);
    dwconv2<<<nb * 600, 256, 0, stream>>>(h1, dw2w, dw2b, y2b, nb);
    sfilt<<<nb * 6, 256, 0, stream>>>(y2b, S2, nb);
    stage2_mfma<<<nb * 2, 512, smem2, stream>>>(y2b, whi, wlo, S2, pw2b, piv2, kk2, kj2, h2);
    fc_out<<<nb * 10, 256, 0, stream>>>(h2, combW, combB, out, b0);
  }
}

// Round 3
// 1618.456 us; speedup vs baseline: 2.3377x; 1.7103x over previous
//
#include <hip/hip_runtime.h>

#define NF1 10
#define NCPF1 3
#define G1 145
#define G2 1506
#define KTOT 1536
#define NKT2 48
#define NS 20  // max distinct channels (slots) per 32-group k-tile, j-major order

typedef __attribute__((ext_vector_type(8))) short bf16x8;
typedef __attribute__((ext_vector_type(4))) float f32x4;
typedef __attribute__((ext_vector_type(4))) int i32x4;

__device__ __forceinline__ ushort rne_bf16(float v) {
  union { float f; uint u; } a; a.f = v;
  return (ushort)((a.u + 0x7fffu + ((a.u >> 16) & 1u)) >> 16);
}
__device__ __forceinline__ float bf_to_f(ushort s) {
  union { uint u; float f; } a; a.u = ((uint)s) << 16;
  return a.f;
}

// ---------------- stage-1 perm tables (i-major, small) ----------------
__global__ void build_tables1(int* __restrict__ piv1, int* __restrict__ kk1, int* __restrict__ kj1) {
  int t = threadIdx.x;
  if (t < NF1) {
    int i = t;
    int base = 0;
    for (int ii = 0; ii < i; ++ii) base += (NF1 - ii) + (NCPF1 - 1) * (NF1 - 1 - ii);
    int count = base;
    for (int j = 0; j < NCPF1; ++j) {
      int k0 = (j == 0) ? i : (i + 1);
      for (int k = k0; k < NF1; ++k) {
        piv1[count] = i * NCPF1 + j;
        kk1[count] = k;
        kj1[count] = k * NCPF1 + j;
        ++count;
      }
    }
  }
}

// ---------------- stage-2 j-major group order + slot tables ----------------
// new order: for j in 0..99: for i: for k in (j==0 ? i..5 : i+1..5)
// gmap[newg] = old group index (for weight permutation), -1 for pad
// gPacked[newg] = pivslot | kjslot<<8 | kk<<16   (slots local to newg's 32-group tile)
// ktileSlot[kt][NS] = chan | ic<<16
__global__ void build_perm2(int* __restrict__ gmap, int* __restrict__ gPacked, int* __restrict__ ktileSlot) {
  int t = threadIdx.x;
  if (t >= NKT2) return;
  int chans[NS];
  int nch = 0;
  int pivs[32], kjs[32], kks[32];
  int base = t * 32;
  for (int u = 0; u < 32; ++u) {
    int g = base + u;
    if (g >= G2) { pivs[u] = -1; gmap[g] = -1; gPacked[g] = 0; continue; }
    int i, j, k;
    if (g < 21) {
      j = 0; int r = g; i = 0; int len = 6;
      while (r >= len) { r -= len; ++i; len = 6 - i; }
      k = i + r;
    } else {
      int gp = g - 21; j = 1 + gp / 15; int r = gp % 15; i = 0; int len = 5;
      while (r >= len) { r -= len; ++i; len = 5 - i; }
      k = i + 1 + r;
    }
    pivs[u] = i * 100 + j; kjs[u] = k * 100 + j; kks[u] = k;
    int ob = (i == 0) ? 0 : (i == 1) ? 501 : (i == 2) ? 902 : (i == 3) ? 1203 : (i == 4) ? 1404 : 1505;
    int old;
    if (j == 0) old = ob + (k - i);
    else old = ob + (6 - i) + (j - 1) * (5 - i) + (k - i - 1);
    gmap[g] = old;
  }
  for (int u = 0; u < 32; ++u) {
    int g = base + u;
    if (g >= G2) continue;
    int ps = -1, ks2 = -1;
    for (int q = 0; q < nch; ++q) {
      if (chans[q] == pivs[u]) ps = q;
      if (chans[q] == kjs[u]) ks2 = q;
    }
    if (ps < 0) { ps = nch; chans[nch++] = pivs[u]; }
    if (ks2 < 0) { ks2 = nch; chans[nch++] = kjs[u]; }
    gPacked[g] = ps | (ks2 << 8) | (kks[u] << 16);
  }
  for (int q = 0; q < NS; ++q) {
    int ch = (q < nch) ? chans[q] : 0;
    ktileSlot[t * NS + q] = ch | ((ch / 6) << 16);
  }
}

// split + column-permute pw2 weights into bf16 hi/lo planes [320][1536]
__global__ __launch_bounds__(256) void prep_w2(const float* __restrict__ pw2w, const int* __restrict__ gmap,
                                               ushort* __restrict__ whi, ushort* __restrict__ wlo) {
  int idx = blockIdx.x * 256 + threadIdx.x;
  if (idx >= 320 * KTOT) return;
  int oc = idx / KTOT, k = idx % KTOT;
  int old = gmap[k];
  float v = (oc < 300 && old >= 0) ? pw2w[oc * G2 + old] : 0.f;
  ushort h = rne_bf16(v);
  union { uint u; float f; } hf; hf.u = ((uint)h) << 16;
  float r = v - hf.f;
  whi[idx] = h;
  wlo[idx] = rne_bf16(r);
}

// pack dw2 weights [600][12]: w0..w8, bias, 0, 0
__global__ __launch_bounds__(256) void prep_dw2(const float* __restrict__ dw2w, const float* __restrict__ dw2b,
                                                float* __restrict__ dw2p) {
  int c = blockIdx.x * 256 + threadIdx.x;
  if (c >= 600) return;
  for (int q = 0; q < 9; ++q) dw2p[c * 12 + q] = dw2w[c * 9 + q];
  dw2p[c * 12 + 9] = dw2b[c];
  dw2p[c * 12 + 10] = 0.f;
  dw2p[c * 12 + 11] = 0.f;
}

// combined filter-sum stencil: wcomb[6][18][9], bcomb[6]
__global__ void prep_wcomb(const float* __restrict__ dw2w, const float* __restrict__ dw2b,
                           float* __restrict__ wcomb, float* __restrict__ bcomb) {
  int idx = threadIdx.x + blockIdx.x * 256;
  if (idx < 6 * 18 * 9) {
    int f = idx / 162, s = (idx % 162) / 9, tap = idx % 9;
    int ic = (f * 100) / 6 + s;
    int clo = f * 100, chi = f * 100 + 100;
    int ilo = ic * 6, ihi = ic * 6 + 6;
    int lo = clo > ilo ? clo : ilo;
    int hi = chi < ihi ? chi : ihi;
    float sacc = 0.f;
    for (int c = lo; c < hi; ++c) sacc += dw2w[c * 9 + tap];
    wcomb[idx] = sacc;
  }
  if (idx < 6) {
    float sacc = 0.f;
    for (int m = 0; m < 100; ++m) sacc += dw2b[idx * 100 + m];
    bcomb[idx] = sacc;
  }
}

// ---------------- stage 1 fused: dwconv1+perm1+pw1+relu+pool -> h1 bf16 ----------------
__global__ __launch_bounds__(256) void stage1f(const float* __restrict__ x, const float* __restrict__ dw1w,
                                               const float* __restrict__ dw1b, const float* __restrict__ pw_w,
                                               const float* __restrict__ pw_b, const int* __restrict__ piv,
                                               const int* __restrict__ kk, const int* __restrict__ kj,
                                               ushort* __restrict__ h1) {
  __shared__ float xs[3][4][34];
  __shared__ float ys[30][64];
  __shared__ float Ss[NF1][64];
  __shared__ float gs[G1][64];
  int b = blockIdx.x >> 4;
  int oh = blockIdx.x & 15;
  int t = threadIdx.x;
  // load x rows 2oh-1 .. 2oh+2 with zero borders
  for (int idx = t; idx < 3 * 4 * 34; idx += 256) {
    int c = idx / 136, rem = idx % 136;
    int r = rem / 34, cc = rem % 34;
    int row = 2 * oh - 1 + r, col = cc - 1;
    float v = 0.f;
    if (row >= 0 && row < 32 && col >= 0 && col < 32) v = x[(((size_t)b * 3 + c) * 32 + row) * 32 + col];
    xs[c][r][cc] = v;
  }
  __syncthreads();
  // y1 rows 2oh, 2oh+1 (30 channels x 64)
  for (int idx = t; idx < 30 * 64; idx += 256) {
    int c = idx >> 6, p = idx & 63;
    int rr = p >> 5, w = p & 31;
    int ic = c / 10;
    float acc = dw1b[c];
#pragma unroll
    for (int kh = 0; kh < 3; ++kh)
#pragma unroll
      for (int kw = 0; kw < 3; ++kw) acc += xs[ic][rr + kh][w + kw] * dw1w[c * 9 + kh * 3 + kw];
    ys[c][p] = acc;
  }
  __syncthreads();
  for (int idx = t; idx < NF1 * 64; idx += 256) {
    int f = idx >> 6, p = idx & 63;
    Ss[f][p] = ys[3 * f][p] + ys[3 * f + 1][p] + ys[3 * f + 2][p];
  }
  __syncthreads();
  for (int idx = t; idx < G1 * 64; idx += 256) {
    int gr = idx >> 6, p = idx & 63;
    float v = ys[piv[gr]][p] + Ss[kk[gr]][p] - ys[kj[gr]][p];
    gs[gr][p] = fmaxf(v, 0.0f);
  }
  __syncthreads();
  for (int item = t; item < 100 * 16; item += 256) {
    int oc = item >> 4, ow = item & 15;
    const float* wr = pw_w + oc * G1;
    float a0 = 0.f, a1 = 0.f, a2 = 0.f, a3 = 0.f;
    for (int gr = 0; gr < G1; ++gr) {
      float wv = wr[gr];
      float2 ga = *(const float2*)&gs[gr][2 * ow];
      float2 gb = *(const float2*)&gs[gr][32 + 2 * ow];
      a0 += wv * ga.x;
      a1 += wv * ga.y;
      a2 += wv * gb.x;
      a3 += wv * gb.y;
    }
    float m = fmaxf(fmaxf(a0, a1), fmaxf(a2, a3)) + pw_b[oc];
    h1[((size_t)b * 100 + oc) * 256 + oh * 16 + ow] = rne_bf16(fmaxf(m, 0.0f));
  }
}

// ---------------- stage 2 fused: dwconv2+S+perm2+pw2(MFMA)+relu+pool -> h2 bf16 ----------------
// grid = nb*2 (two 160-oc halves), block 512 = 8 waves (2M x 4N)
__global__ __launch_bounds__(512, 1) void stage2f(
    const ushort* __restrict__ h1, const ushort* __restrict__ whi, const ushort* __restrict__ wlo,
    const float* __restrict__ dw2p, const float* __restrict__ wcomb, const float* __restrict__ bcomb,
    const float* __restrict__ pw2b, const int* __restrict__ gPacked, const int* __restrict__ ktileSlot,
    ushort* __restrict__ h2) {
  extern __shared__ char smem[];
  ushort* h1s = (ushort*)smem;                    // [100][18][20] zero-padded  72000 B
  float* y2c = (float*)(smem + 72000);            // [NS][264]                  21120 B
  ushort* ghh = (ushort*)(smem + 93120);          // [256][32] swizzled bf16 hi 16384 B
  ushort* gll = (ushort*)(smem + 109504);         // lo plane                   16384 B
  float* Slp = (float*)(smem + 125888);           // [6][264] filter sums        6336 B
  int* gPk = (int*)(smem + 132224);               // [1536]                      6144 B
  int* kts = (int*)(smem + 138368);               // [48][NS]                    3840 B

  int b = blockIdx.x >> 1, mg = blockIdx.x & 1;
  int t = threadIdx.x;
  int lane = t & 63, wave = t >> 6;
  int wm = wave >> 2, wn = wave & 3;
  int lrow = lane & 15, lkk = lane >> 4;

  for (int i = t; i < 1536; i += 512) gPk[i] = gPacked[i];
  for (int i = t; i < NKT2 * NS; i += 512) kts[i] = ktileSlot[i];
  for (int i = t; i < 18000; i += 512) ((uint*)h1s)[i] = 0u;
  __syncthreads();
  // load h1 -> padded LDS (true (h,w) at padded (h+1, w+2))
  const ushort* hb = h1 + (size_t)b * 25600;
  for (int i = t; i < 1600; i += 512) {
    int ic = i >> 4, h = i & 15;
    const uint* src = (const uint*)(hb + ic * 256 + h * 16);
    uint* dst = (uint*)(h1s + ic * 360 + (h + 1) * 20 + 2);
#pragma unroll
    for (int q = 0; q < 8; ++q) dst[q] = src[q];
  }
  __syncthreads();
  // filter sums S via combined stencil (fp32)
  for (int i = t; i < 6 * 256; i += 512) {
    int f = i >> 8, p = i & 255;
    int h = p >> 4, w = p & 15;
    int iclo = (f * 100) / 6;
    float s = bcomb[f];
    for (int ss = 0; ss < 18; ++ss) {
      int ic = iclo + ss;
      if (ic > 99) ic = 99;  // weights are zero there
      int base = ic * 360 + h * 20 + w + 1;
      const float* wv = wcomb + (f * 18 + ss) * 9;
#pragma unroll
      for (int dh = 0; dh < 3; ++dh)
#pragma unroll
        for (int dw = 0; dw < 3; ++dw) s += wv[dh * 3 + dw] * bf_to_f(h1s[base + dh * 20 + dw]);
    }
    Slp[f * 264 + p] = s;
  }

  f32x4 acc[5][4];
#pragma unroll
  for (int mt = 0; mt < 5; ++mt)
#pragma unroll
    for (int nt = 0; nt < 4; ++nt) acc[mt][nt] = (f32x4){0.f, 0.f, 0.f, 0.f};

  for (int kt = 0; kt < NKT2; ++kt) {
    // ---- C1: stage this tile's distinct channels y2c[slot][256] (fp32, fused dwconv2) ----
    if (t < NS * 16) {
      int slot = t >> 4, h = t & 15;
      int ci = kts[kt * NS + slot];
      int chan = ci & 0xffff, ic = ci >> 16;
      const float4* wp4 = (const float4*)(dw2p + chan * 12);
      float4 wa = wp4[0], wb = wp4[1], wc = wp4[2];
      float fr[3][20];
#pragma unroll
      for (int r = 0; r < 3; ++r) {
        const unsigned long long* rp = (const unsigned long long*)(h1s + ic * 360 + (h + r) * 20);
#pragma unroll
        for (int q = 0; q < 5; ++q) {
          unsigned long long v = rp[q];
#pragma unroll
          for (int e = 0; e < 4; ++e) {
            union { uint u; float f; } cv;
            cv.u = ((uint)(v >> (16 * e)) & 0xffffu) << 16;
            fr[r][q * 4 + e] = cv.f;
          }
        }
      }
      float outv[16];
#pragma unroll
      for (int w = 0; w < 16; ++w) {
        float s = wc.y;
        s += fr[0][w + 1] * wa.x + fr[0][w + 2] * wa.y + fr[0][w + 3] * wa.z;
        s += fr[1][w + 1] * wa.w + fr[1][w + 2] * wb.x + fr[1][w + 3] * wb.y;
        s += fr[2][w + 1] * wb.z + fr[2][w + 2] * wb.w + fr[2][w + 3] * wc.x;
        outv[w] = s;
      }
      float* dst = y2c + slot * 264 + h * 16;
#pragma unroll
      for (int q = 0; q < 4; ++q) {
        float4 f4;
        f4.x = outv[q * 4]; f4.y = outv[q * 4 + 1]; f4.z = outv[q * 4 + 2]; f4.w = outv[q * 4 + 3];
        *(float4*)(dst + q * 4) = f4;
      }
    }
    __syncthreads();
    // ---- C2: G assembly -> swizzled bf16 hi/lo planes ----
    {
      int nn = t & 255;
#pragma unroll
      for (int oc8 = 0; oc8 < 2; ++oc8) {
        int oct = (t >> 8) + oc8 * 2;
        const i32x4* pkp = (const i32x4*)&gPk[kt * 32 + oct * 8];
        i32x4 pa = pkp[0], pb = pkp[1];
        union { ushort s[8]; bf16x8 v; } ph, pl;
#pragma unroll
        for (int c = 0; c < 8; ++c) {
          int pk = (c < 4) ? pa[c] : pb[c - 4];
          int ps = pk & 255, ks = (pk >> 8) & 255, kf = (pk >> 16) & 255;
          float v = y2c[ps * 264 + nn] + Slp[kf * 264 + nn] - y2c[ks * 264 + nn];
          v = fmaxf(v, 0.f);
          union { float f; uint u; } a; a.f = v;
          uint hu = (a.u + 0x7fffu + ((a.u >> 16) & 1u)) >> 16;
          union { uint u; float f; } hf; hf.u = hu << 16;
          float r = v - hf.f;
          union { float f; uint u; } b2; b2.f = r;
          ph.s[c] = (ushort)hu;
          pl.s[c] = (ushort)(b2.u >> 16);
        }
        uint off = (uint)(nn * 64) + ((((uint)oct) * 16u) ^ (((uint)nn & 3u) << 4));
        *(bf16x8*)((char*)ghh + off) = ph.v;
        *(bf16x8*)((char*)gll + off) = pl.v;
      }
    }
    __syncthreads();
    // ---- C3/C4: B fragments + MFMA ----
    {
      bf16x8 Bh[4], Bl[4];
#pragma unroll
      for (int nt = 0; nt < 4; ++nt) {
        int n = wn * 64 + nt * 16 + lrow;
        uint off = (uint)(n * 64) + ((((uint)lkk) * 16u) ^ (((uint)n & 3u) << 4));
        Bh[nt] = *(const bf16x8*)((char*)ghh + off);
        Bl[nt] = *(const bf16x8*)((char*)gll + off);
      }
#pragma unroll
      for (int mt = 0; mt < 5; ++mt) {
        int row = mg * 160 + wm * 80 + mt * 16 + lrow;
        const bf16x8 Ah = *(const bf16x8*)(whi + (size_t)row * KTOT + kt * 32 + lkk * 8);
        const bf16x8 Al = *(const bf16x8*)(wlo + (size_t)row * KTOT + kt * 32 + lkk * 8);
#pragma unroll
        for (int nt = 0; nt < 4; ++nt) {
          f32x4 c = acc[mt][nt];
          c = __builtin_amdgcn_mfma_f32_16x16x32_bf16(Ah, Bh[nt], c, 0, 0, 0);
          c = __builtin_amdgcn_mfma_f32_16x16x32_bf16(Ah, Bl[nt], c, 0, 0, 0);
          c = __builtin_amdgcn_mfma_f32_16x16x32_bf16(Al, Bh[nt], c, 0, 0, 0);
          acc[mt][nt] = c;
        }
      }
    }
    __syncthreads();
  }

  // ---- epilogue: 2x2 pool (nt-pair + lane shuffle), bias, relu, bf16 store ----
#pragma unroll
  for (int mt = 0; mt < 5; ++mt) {
    int ocb = mg * 160 + wm * 80 + mt * 16 + lkk * 4;
#pragma unroll
    for (int hp2 = 0; hp2 < 2; ++hp2) {
#pragma unroll
      for (int r = 0; r < 4; ++r) {
        float v = fmaxf(acc[mt][hp2 * 2][r], acc[mt][hp2 * 2 + 1][r]);
        float v2 = fmaxf(v, __shfl_xor(v, 1));
        int oc = ocb + r;
        if ((lane & 1) == 0 && oc < 300) {
          float o = fmaxf(v2 + pw2b[oc], 0.f);
          int oh = wn * 2 + hp2, ow = lrow >> 1;
          h2[((size_t)b * 300 + oc) * 64 + oh * 8 + ow] = rne_bf16(o);
        }
      }
    }
  }
}

// ---------------- FC (folded fc2@fc1) ----------------
__global__ __launch_bounds__(256) void fold_fc(const float* __restrict__ fc1w, const float* __restrict__ fc2w,
                                               float* __restrict__ combW) {
  int idx = blockIdx.x * 256 + threadIdx.x;
  if (idx >= 10 * 19200) return;
  int o = idx / 19200, c = idx % 19200;
  float s = 0.f;
  for (int m = 0; m < 120; ++m) s += fc2w[o * 120 + m] * fc1w[m * 19200 + c];
  combW[idx] = s;
}

__global__ void fold_b(const float* __restrict__ fc1b, const float* __restrict__ fc2w,
                       const float* __restrict__ fc2b, float* __restrict__ combB) {
  int o = threadIdx.x;
  if (o < 10) {
    float s = fc2b[o];
    for (int m = 0; m < 120; ++m) s += fc2w[o * 120 + m] * fc1b[m];
    combB[o] = s;
  }
}

__global__ __launch_bounds__(256) void fc_out(const ushort* __restrict__ h2, const float* __restrict__ combW,
                                              const float* __restrict__ combB, float* __restrict__ out, int b0) {
  int b = blockIdx.x / 10, o = blockIdx.x % 10;
  const ushort* hp = h2 + (size_t)b * 19200;
  const float* wp = combW + (size_t)o * 19200;
  float s = 0.f;
  for (int idx = threadIdx.x; idx < 2400; idx += 256) {
    bf16x8 hv = *(const bf16x8*)(hp + idx * 8);
    float4 w0 = *(const float4*)(wp + idx * 8);
    float4 w1 = *(const float4*)(wp + idx * 8 + 4);
    s += bf_to_f((ushort)hv[0]) * w0.x + bf_to_f((ushort)hv[1]) * w0.y;
    s += bf_to_f((ushort)hv[2]) * w0.z + bf_to_f((ushort)hv[3]) * w0.w;
    s += bf_to_f((ushort)hv[4]) * w1.x + bf_to_f((ushort)hv[5]) * w1.y;
    s += bf_to_f((ushort)hv[6]) * w1.z + bf_to_f((ushort)hv[7]) * w1.w;
  }
  __shared__ float red[256];
  red[threadIdx.x] = s;
  __syncthreads();
  for (int stride = 128; stride > 0; stride >>= 1) {
    if (threadIdx.x < stride) red[threadIdx.x] += red[threadIdx.x + stride];
    __syncthreads();
  }
  if (threadIdx.x == 0) out[(size_t)(b0 + b) * 10 + o] = red[0] + combB[o];
}

extern "C" void kernel_launch(void* const* d_in, const int* in_sizes, int n_in,
                              void* d_out, int out_size, void* d_ws, size_t ws_size,
                              hipStream_t stream) {
  const float* x = (const float*)d_in[0];
  const float* dw1w = (const float*)d_in[1];
  const float* dw1b = (const float*)d_in[2];
  const float* pw1w = (const float*)d_in[3];
  const float* pw1b = (const float*)d_in[4];
  const float* dw2w = (const float*)d_in[5];
  const float* dw2b = (const float*)d_in[6];
  const float* pw2w = (const float*)d_in[7];
  const float* pw2b = (const float*)d_in[8];
  const float* fc1w = (const float*)d_in[9];
  const float* fc1b = (const float*)d_in[10];
  const float* fc2w = (const float*)d_in[11];
  const float* fc2b = (const float*)d_in[12];
  float* out = (float*)d_out;

  char* ws = (char*)d_ws;
  size_t off = 0;
  auto alloc = [&](size_t bytes) -> void* {
    off = (off + 255) & ~(size_t)255;
    void* p = ws + off;
    off += bytes;
    return p;
  };
  int* piv1 = (int*)alloc(G1 * 4);
  int* kk1 = (int*)alloc(G1 * 4);
  int* kj1 = (int*)alloc(G1 * 4);
  int* gmap = (int*)alloc(KTOT * 4);
  int* gPacked = (int*)alloc(KTOT * 4);
  int* ktileSlot = (int*)alloc(NKT2 * NS * 4);
  float* combW = (float*)alloc((size_t)10 * 19200 * 4);
  float* combB = (float*)alloc(16 * 4);
  ushort* whi = (ushort*)alloc((size_t)320 * KTOT * 2);
  ushort* wlo = (ushort*)alloc((size_t)320 * KTOT * 2);
  float* dw2p = (float*)alloc((size_t)600 * 12 * 4);
  float* wcombp = (float*)alloc((size_t)6 * 18 * 9 * 4);
  float* bcombp = (float*)alloc(8 * 4);
  size_t static_end = (off + 255) & ~(size_t)255;

  // per-image: h1 bf16 [100][256] = 51200 B, h2 bf16 [300][64] = 38400 B
  size_t per_img = 51200 + 38400;
  long long avail = (long long)ws_size - (long long)static_end - 4096;
  int CB = 1;
  if (avail > 0) {
    long long c = avail / (long long)(per_img + 512);
    if (c > 125) c = 125;  // 250-block stage2 grid; 4 even chunks at 500
    if (c < 1) c = 1;
    CB = (int)c;
  }
  ushort* h1 = (ushort*)alloc((size_t)CB * 25600 * 2);
  ushort* h2 = (ushort*)alloc((size_t)CB * 19200 * 2);

  const uint SMEM2 = 142208;
  hipFuncSetAttribute((const void*)stage2f, hipFuncAttributeMaxDynamicSharedMemorySize, (int)SMEM2);

  build_tables1<<<1, 64, 0, stream>>>(piv1, kk1, kj1);
  build_perm2<<<1, 64, 0, stream>>>(gmap, gPacked, ktileSlot);
  prep_dw2<<<3, 256, 0, stream>>>(dw2w, dw2b, dw2p);
  prep_wcomb<<<4, 256, 0, stream>>>(dw2w, dw2b, wcombp, bcombp);
  prep_w2<<<(320 * KTOT + 255) / 256, 256, 0, stream>>>(pw2w, gmap, whi, wlo);
  fold_fc<<<(10 * 19200 + 255) / 256, 256, 0, stream>>>(fc1w, fc2w, combW);
  fold_b<<<1, 64, 0, stream>>>(fc1b, fc2w, fc2b, combB);

  for (int b0 = 0; b0 < 500; b0 += CB) {
    int nb = 500 - b0 < CB ? 500 - b0 : CB;
    stage1f<<<nb * 16, 256, 0, stream>>>(x + (size_t)b0 * 3 * 1024, dw1w, dw1b, pw1w, pw1b,
                                         piv1, kk1, kj1, h1);
    stage2f<<<nb * 2, 512, SMEM2, stream>>>(h1, whi, wlo, dw2p, wcombp, bcombp, pw2b,
                                            gPacked, ktileSlot, h2);
    fc_out<<<nb * 10, 256, 0, stream>>>(h2, combW, combB, out, b0);
  }
}